// Round 1
// baseline (837.207 us; speedup 1.0000x reference)
//
#include <hip/hip_runtime.h>
#include <hip/hip_bf16.h>

typedef __bf16 bf16x8 __attribute__((ext_vector_type(8)));
typedef float  f32x4  __attribute__((ext_vector_type(4)));

#define B_   16
#define CIN  64
#define COUT 64
#define H_   256
#define W_   256

// ---------------- Kernel 1: modulate + demodulate weights -> bf16 [b][tap][co][ci]
__global__ void modw_kernel(const float* __restrict__ weight,
                            const float* __restrict__ y,
                            __bf16* __restrict__ w1g) {
  const int co = blockIdx.x;
  const int b  = blockIdx.y;
  const int ci = threadIdx.x;               // 64 threads = 1 wave
  const float c  = 0.041666666666666664f;   // (64*9)^-0.5 = 1/24
  const float yv = y[b*CIN + ci] * c;
  float w[9];
  float s = 0.0f;
#pragma unroll
  for (int t = 0; t < 9; ++t) {
    float wv = weight[(co*CIN + ci)*9 + t] * yv;
    w[t] = wv;
    s += wv * wv;
  }
#pragma unroll
  for (int off = 32; off > 0; off >>= 1) s += __shfl_xor(s, off, 64);
  const float d = rsqrtf(s + 1e-8f);
#pragma unroll
  for (int t = 0; t < 9; ++t)
    w1g[((b*9 + t)*COUT + co)*CIN + ci] = (__bf16)(w[t] * d);
}

// ---------------- Kernel 2: implicit-GEMM conv, one (b, y0) row per block
// LDS layout: xs[px_lds][ci], px_lds = px+1 (cols 0 and 257 are zero pads),
// ci stored as 8 groups of 8, group g placed at slot g ^ (px_lds & 7)  (bank swizzle).
__global__ __launch_bounds__(128, 2)
void conv_kernel(const float* __restrict__ X,
                 const __bf16* __restrict__ w1g,
                 float* __restrict__ out) {
  const int y0   = blockIdx.x;
  const int b    = blockIdx.y;
  const int tid  = threadIdx.x;
  const int lane = tid & 63;
  const int wv   = tid >> 6;      // wave 0..1
  const int q    = lane >> 4;     // 0..3
  const int n    = lane & 15;     // 0..15

  __shared__ __bf16 xs[258 * 64];

  f32x4 acc[2][16];
#pragma unroll
  for (int ct = 0; ct < 2; ++ct)
#pragma unroll
    for (int nt = 0; nt < 16; ++nt)
      acc[ct][nt] = (f32x4){0.f, 0.f, 0.f, 0.f};

  if (tid < 64) {                 // zero pad columns px_lds = 0 and 257
    xs[tid] = (__bf16)0.f;
    xs[257 * 64 + tid] = (__bf16)0.f;
  }

  const int px_base = 4 * (tid & 63);   // each thread stages 4 consecutive px

  for (int dy = 0; dy < 3; ++dy) {
    const int yin = y0 + dy - 1;
    const bool valid = (yin >= 0) && (yin < H_);
    const float* xrow = valid ? (X + ((long)b * (CIN * H_ * W_) + (long)yin * W_)) : X;

    // ---- stage one input row (all 64 ci) into LDS as bf16, px-major ----
#pragma unroll
    for (int rep = 0; rep < 4; ++rep) {
      const int cg = wv + 2 * rep;      // ci group 0..7 (8 ci each)
      bf16x8 frag[4];
      if (valid) {
        float4 f[8];
#pragma unroll
        for (int j = 0; j < 8; ++j)
          f[j] = *reinterpret_cast<const float4*>(xrow + (long)(cg * 8 + j) * (H_ * W_) + px_base);
#pragma unroll
        for (int j = 0; j < 8; ++j) {
          frag[0][j] = (__bf16)f[j].x;
          frag[1][j] = (__bf16)f[j].y;
          frag[2][j] = (__bf16)f[j].z;
          frag[3][j] = (__bf16)f[j].w;
        }
      } else {
#pragma unroll
        for (int o = 0; o < 4; ++o)
#pragma unroll
          for (int j = 0; j < 8; ++j) frag[o][j] = (__bf16)0.f;
      }
#pragma unroll
      for (int oo = 0; oo < 4; ++oo) {
        const int o  = (oo + lane) & 3;           // rotate to spread write banks
        const int pl = px_base + o + 1;
        const int gs = cg ^ (pl & 7);             // XOR swizzle
        *reinterpret_cast<bf16x8*>(&xs[pl * 64 + gs * 8]) = frag[o];
      }
    }
    __syncthreads();

    // ---- A fragments for this dy's 3 taps (2 co-tiles per wave, 2 K-steps) ----
    bf16x8 afr[2][3][2];
#pragma unroll
    for (int c2 = 0; c2 < 2; ++c2) {
      const int co = (wv * 2 + c2) * 16 + n;      // m = lane&15
#pragma unroll
      for (int dx = 0; dx < 3; ++dx) {
        const int tap = dy * 3 + dx;
        const __bf16* wp = w1g + ((b * 9 + tap) * COUT + co) * CIN + q * 8;
        afr[c2][dx][0] = *reinterpret_cast<const bf16x8*>(wp);        // ci = q*8+j
        afr[c2][dx][1] = *reinterpret_cast<const bf16x8*>(wp + 32);   // ci = 32+q*8+j
      }
    }

    // ---- MFMA sweep: 3 dx taps x 16 px-tiles x 2 K-steps, B reused by 2 co-tiles ----
#pragma unroll
    for (int dx = 0; dx < 3; ++dx) {
      const int p3    = (n + dx) & 7;
      const int base0 = (n + dx) * 64 + ((q ^ p3)) * 8;        // ks=0: group q
      const int base1 = (n + dx) * 64 + (((q + 4) ^ p3)) * 8;  // ks=1: group q+4
#pragma unroll
      for (int nt = 0; nt < 16; ++nt) {
        const bf16x8 b0 = *reinterpret_cast<const bf16x8*>(&xs[nt * 1024 + base0]);
        const bf16x8 b1 = *reinterpret_cast<const bf16x8*>(&xs[nt * 1024 + base1]);
        acc[0][nt] = __builtin_amdgcn_mfma_f32_16x16x32_bf16(afr[0][dx][0], b0, acc[0][nt], 0, 0, 0);
        acc[0][nt] = __builtin_amdgcn_mfma_f32_16x16x32_bf16(afr[0][dx][1], b1, acc[0][nt], 0, 0, 0);
        acc[1][nt] = __builtin_amdgcn_mfma_f32_16x16x32_bf16(afr[1][dx][0], b0, acc[1][nt], 0, 0, 0);
        acc[1][nt] = __builtin_amdgcn_mfma_f32_16x16x32_bf16(afr[1][dx][1], b1, acc[1][nt], 0, 0, 0);
      }
    }
    __syncthreads();
  }

  // ---- epilogue: C/D layout col=lane&15 (px), row=(lane>>4)*4+r (co) ----
#pragma unroll
  for (int c2 = 0; c2 < 2; ++c2) {
    const int co = (wv * 2 + c2) * 16 + q * 4;
#pragma unroll
    for (int r = 0; r < 4; ++r) {
      float* op = out + ((long)(b * COUT + co + r) * H_ + y0) * W_ + n;
#pragma unroll
      for (int nt = 0; nt < 16; ++nt)
        op[nt * 16] = acc[c2][nt][r];
    }
  }
}

extern "C" void kernel_launch(void* const* d_in, const int* in_sizes, int n_in,
                              void* d_out, int out_size, void* d_ws, size_t ws_size,
                              hipStream_t stream) {
  const float* X = (const float*)d_in[0];   // (16, 64, 256, 256) fp32
  const float* y = (const float*)d_in[1];   // (16, 64) fp32
  const float* w = (const float*)d_in[2];   // (64, 64, 3, 3) fp32
  float* outp = (float*)d_out;              // (16, 64, 256, 256) fp32
  __bf16* w1g = (__bf16*)d_ws;              // 16*9*64*64 bf16 = 1.13 MB scratch

  modw_kernel<<<dim3(COUT, B_), 64, 0, stream>>>(w, y, w1g);
  conv_kernel<<<dim3(H_, B_), 128, 0, stream>>>(X, w1g, outp);
}